// Round 2
// baseline (194.138 us; speedup 1.0000x reference)
//
#include <hip/hip_runtime.h>
#include <hip/hip_bf16.h>

#define BETA_LOG2E 14.426950408889634f   // 10 * log2(e)
#define EPSN 1e-6f

typedef __bf16 bf16x8 __attribute__((ext_vector_type(8)));
typedef float  f32x4  __attribute__((ext_vector_type(4)));

static __device__ inline unsigned int pack2bf(float a, float b) {
    __hip_bfloat16 ha = __float2bfloat16(a);
    __hip_bfloat16 hb = __float2bfloat16(b);
    return (unsigned int)__builtin_bit_cast(unsigned short, ha) |
           ((unsigned int)__builtin_bit_cast(unsigned short, hb) << 16);
}

// ---------------------------------------------------------------------------
// Kernel 1: L2-normalize over C, transpose [b][c][n] -> [b][n][c], cast bf16.
// aT additionally pre-scaled by BETA*log2(e) (single rounding).
// LDS f32 tile [n][c] stride 260; phase2: ds_read_b128 + coalesced uint4 out.
// ---------------------------------------------------------------------------
__global__ __launch_bounds__(256) void k_norm_transpose(
    const float* __restrict__ f0, const float* __restrict__ f1,
    unsigned short* __restrict__ aT, unsigned short* __restrict__ bT)
{
    __shared__ float tile[64 * 260];      // [n][c], stride 260 (16B-aligned rows)
    __shared__ float partial[16 * 64];    // [cg][n]
    __shared__ float scale_s[64];

    int idx   = blockIdx.x;
    int which = idx >> 8;
    int rem   = idx & 255;
    int b     = rem >> 6;
    int n0    = (rem & 63) * 64;
    const float4* src4 = (const float4*)(which ? f1 : f0);
    unsigned short* dst = which ? bT : aT;

    int t  = threadIdx.x;
    int n4 = t & 15;       // float4 index over n
    int cg = t >> 4;       // 16 channel groups x 16 c

    f32x4 ssv = {0.f, 0.f, 0.f, 0.f};
#pragma unroll
    for (int i = 0; i < 16; ++i) {
        int c = i * 16 + cg;
        float4 v = src4[(size_t)(b * 256 + c) * 1024 + (n0 >> 2) + n4];
        tile[(n4 * 4 + 0) * 260 + c] = v.x;
        tile[(n4 * 4 + 1) * 260 + c] = v.y;
        tile[(n4 * 4 + 2) * 260 + c] = v.z;
        tile[(n4 * 4 + 3) * 260 + c] = v.w;
        ssv.x += v.x * v.x;  ssv.y += v.y * v.y;
        ssv.z += v.z * v.z;  ssv.w += v.w * v.w;
    }
    *reinterpret_cast<f32x4*>(&partial[cg * 64 + n4 * 4]) = ssv;
    __syncthreads();
    if (t < 64) {
        float s = 0.f;
#pragma unroll
        for (int g = 0; g < 16; ++g) s += partial[g * 64 + t];
        scale_s[t] = (which ? 1.0f : BETA_LOG2E) / fmaxf(sqrtf(s), EPSN);
    }
    __syncthreads();

#pragma unroll
    for (int it = 0; it < 8; ++it) {
        int n    = it * 8 + (t >> 5);
        int cgrp = t & 31;
        float sc = scale_s[n];
        const float* row = &tile[n * 260 + cgrp * 8];
        float4 u = *reinterpret_cast<const float4*>(row);
        float4 w = *reinterpret_cast<const float4*>(row + 4);
        uint4 o;
        o.x = pack2bf(u.x * sc, u.y * sc);
        o.y = pack2bf(u.z * sc, u.w * sc);
        o.z = pack2bf(w.x * sc, w.y * sc);
        o.w = pack2bf(w.z * sc, w.w * sc);
        *reinterpret_cast<uint4*>(&dst[(size_t)(b * 4096 + n0 + n) * 256 + cgrp * 8]) = o;
    }
}

// ---------------------------------------------------------------------------
// Kernel 2: flash cosine-sim + online softmax stats (no-max-needed: |logit|<=14.43).
// grid = 128*nks blocks: 4 batch x 32 qtile(128q) x nks keysplits.
// stats[q][ks] = {Z, Sx, Sy, Pmax}; aT pre-scaled so p = exp2(acc).
// ---------------------------------------------------------------------------
__global__ __launch_bounds__(256, 4) void k_flash(
    const unsigned short* __restrict__ aT, const unsigned short* __restrict__ bT,
    float* __restrict__ stats, int nks, int lg)
{
    __shared__ unsigned short kbuf[64 * 272];  // 64 keys x 272 hw (544 B rows)

    int idx   = blockIdx.x;
    int xcd   = idx & 7;                 // XCD swizzle: batch -> 2 XCDs
    int batch = xcd >> 1;
    int sub   = ((idx >> 3) << 1) | (xcd & 1);   // [0, 32*nks)
    int qt    = sub >> lg;               // [0,32)
    int ks    = sub & (nks - 1);         // [0,nks)
    int kps   = 4096 >> lg;              // keys per split
    int chunks = kps >> 6;

    int t    = threadIdx.x;
    int w    = t >> 6;
    int lane = t & 63;
    int quad = lane >> 4;
    int l15  = lane & 15;
    int q0w  = qt * 128 + w * 32;
    int k0   = ks * kps;

    // resident A fragments: 2 strips of 16 queries x 8 K-steps
    bf16x8 afrag[2][8];
#pragma unroll
    for (int s = 0; s < 2; ++s) {
        const unsigned short* ap =
            aT + ((size_t)(batch * 4096 + q0w + s * 16 + l15)) * 256 + quad * 8;
#pragma unroll
        for (int kk = 0; kk < 8; ++kk)
            afrag[s][kk] = *reinterpret_cast<const bf16x8*>(ap + kk * 32);
    }

    float Z[8], Sx[8], Sy[8], Pm[8], Zc[8];
#pragma unroll
    for (int i = 0; i < 8; ++i) { Z[i] = 0.f; Sx[i] = 0.f; Sy[i] = 0.f; Pm[i] = 0.f; Zc[i] = 0.f; }

    float kxl = (float)l15;

    for (int ch = 0; ch < chunks; ++ch) {
        int kbase = k0 + ch * 64;
        const unsigned short* gsrc = bT + ((size_t)(batch * 4096 + kbase)) * 256;
#pragma unroll
        for (int i = 0; i < 8; ++i) {
            int h = i * 2048 + t * 8;
            uint4 v = *reinterpret_cast<const uint4*>(gsrc + h);
            int key  = i * 8 + (t >> 5);
            int gran = t & 31;
            *reinterpret_cast<uint4*>(&kbuf[key * 272 + gran * 8]) = v;
        }
        __syncthreads();

#pragma unroll
        for (int nt = 0; nt < 4; ++nt) {
            f32x4 acc0 = {0.f, 0.f, 0.f, 0.f};
            f32x4 acc1 = {0.f, 0.f, 0.f, 0.f};
            const unsigned short* lp = &kbuf[(nt * 16 + l15) * 272 + quad * 8];
#pragma unroll
            for (int kk = 0; kk < 8; ++kk) {
                bf16x8 bfrag = *reinterpret_cast<const bf16x8*>(lp + kk * 32);
                acc0 = __builtin_amdgcn_mfma_f32_16x16x32_bf16(afrag[0][kk], bfrag, acc0, 0, 0, 0);
                acc1 = __builtin_amdgcn_mfma_f32_16x16x32_bf16(afrag[1][kk], bfrag, acc1, 0, 0, 0);
            }
            float kx = (float)(nt * 16) + kxl;   // key & 63 (kbase multiple of 64)
#pragma unroll
            for (int r = 0; r < 4; ++r) {
                float p0 = exp2f(acc0[r]);
                Z[r] += p0;  Sx[r] += p0 * kx;  Pm[r] = fmaxf(Pm[r], p0);
                float p1 = exp2f(acc1[r]);
                Z[4 + r] += p1;  Sx[4 + r] += p1 * kx;  Pm[4 + r] = fmaxf(Pm[4 + r], p1);
            }
        }
        __syncthreads();

        float ky = (float)(ks * chunks + ch);    // key >> 6, constant per chunk
#pragma unroll
        for (int i = 0; i < 8; ++i) {
            Sy[i] += ky * (Z[i] - Zc[i]);
            Zc[i] = Z[i];
        }
    }

    // reduce across the 16 col-lanes
#pragma unroll
    for (int i = 0; i < 8; ++i) {
#pragma unroll
        for (int m = 1; m <= 8; m <<= 1) {
            Z[i]  += __shfl_xor(Z[i], m);
            Sx[i] += __shfl_xor(Sx[i], m);
            Sy[i] += __shfl_xor(Sy[i], m);
            Pm[i]  = fmaxf(Pm[i], __shfl_xor(Pm[i], m));
        }
    }
    if (l15 == 0) {
#pragma unroll
        for (int s = 0; s < 2; ++s)
#pragma unroll
            for (int r = 0; r < 4; ++r) {
                int q = q0w + s * 16 + quad * 4 + r;
                f32x4 st = {Z[s * 4 + r], Sx[s * 4 + r], Sy[s * 4 + r], Pm[s * 4 + r]};
                *reinterpret_cast<f32x4*>(
                    &stats[((size_t)(batch * 4096 + q) * nks + ks) * 4]) = st;
            }
    }
}

// ---------------------------------------------------------------------------
// Kernel 3: merge key-splits, write warp (x,y interleaved) then cert.
// ---------------------------------------------------------------------------
__global__ __launch_bounds__(256) void k_finalize(
    const float* __restrict__ stats, float* __restrict__ out, int nks)
{
    int q = blockIdx.x * 256 + threadIdx.x;   // [0, 16384)
    const f32x4* s = reinterpret_cast<const f32x4*>(stats + (size_t)q * 4 * nks);
    float Z = 0.f, Sx = 0.f, Sy = 0.f, Pm = 0.f;
    for (int i = 0; i < nks; ++i) {
        f32x4 a = s[i];
        Z += a.x;  Sx += a.y;  Sy += a.z;  Pm = fmaxf(Pm, a.w);
    }
    float invZ = 1.0f / Z;
    out[q * 2 + 0]  = Sx * invZ;
    out[q * 2 + 1]  = Sy * invZ;
    out[32768 + q]  = Pm * invZ;
}

extern "C" void kernel_launch(void* const* d_in, const int* in_sizes, int n_in,
                              void* d_out, int out_size, void* d_ws, size_t ws_size,
                              hipStream_t stream)
{
    const float* f0 = (const float*)d_in[0];
    const float* f1 = (const float*)d_in[1];
    unsigned short* aT = (unsigned short*)d_ws;          // 8.39 MB
    unsigned short* bT = aT + (size_t)4 * 4096 * 256;    // 8.39 MB
    float* stats = (float*)(bT + (size_t)4 * 4096 * 256);
    float* out = (float*)d_out;

    size_t base = (size_t)2 * 4 * 4096 * 256 * 2;
    int nks = (ws_size >= base + (size_t)16384 * 8 * 16) ? 8 : 4;
    int lg  = (nks == 8) ? 3 : 2;

    hipLaunchKernelGGL(k_norm_transpose, dim3(512), dim3(256), 0, stream, f0, f1, aT, bT);
    hipLaunchKernelGGL(k_flash, dim3(128 * nks), dim3(256), 0, stream, aT, bT, stats, nks, lg);
    hipLaunchKernelGGL(k_finalize, dim3(64), dim3(256), 0, stream, stats, out, nks);
}

// Round 3
// 140.380 us; speedup vs baseline: 1.3829x; 1.3829x over previous
//
#include <hip/hip_runtime.h>
#include <hip/hip_bf16.h>

#define BETA_LOG2E 14.426950408889634f   // 10 * log2(e)
#define EPSN 1e-6f

typedef __bf16 bf16x8 __attribute__((ext_vector_type(8)));
typedef float  f32x4  __attribute__((ext_vector_type(4)));

static __device__ inline unsigned int pack2bf(float a, float b) {
    __hip_bfloat16 ha = __float2bfloat16(a);
    __hip_bfloat16 hb = __float2bfloat16(b);
    return (unsigned int)__builtin_bit_cast(unsigned short, ha) |
           ((unsigned int)__builtin_bit_cast(unsigned short, hb) << 16);
}

// ---------------------------------------------------------------------------
// Kernel 1: L2-normalize over C, transpose [b][c][n] -> [b][n][c], cast bf16.
// aT pre-scaled by BETA*log2(e). LDS tile [n][256] f32 with additive granule
// swizzle g' = (g + (n>>2)) & 63: phase-1 scalar writes 2-way (free),
// phase-2 b128 reads tile all 32 banks per 8-lane group (m97 pattern).
// ---------------------------------------------------------------------------
__global__ __launch_bounds__(256) void k_norm_transpose(
    const float* __restrict__ f0, const float* __restrict__ f1,
    unsigned short* __restrict__ aT, unsigned short* __restrict__ bT)
{
    __shared__ float tile[64 * 256];      // [n][granule-swizzled c], 64 KB
    __shared__ float partial[16 * 64];    // [cg][n]
    __shared__ float scale_s[64];

    int idx   = blockIdx.x;
    int which = idx >> 8;
    int rem   = idx & 255;
    int b     = rem >> 6;
    int n0    = (rem & 63) * 64;
    const float4* src4 = (const float4*)(which ? f1 : f0);
    unsigned short* dst = which ? bT : aT;

    int t   = threadIdx.x;
    int n4l = t & 15;      // float4-over-n index (n = n4l*4 + r)
    int cg  = t >> 4;      // 16 channel groups x 16 c

    f32x4 ssv = {0.f, 0.f, 0.f, 0.f};
#pragma unroll
    for (int i = 0; i < 16; ++i) {
        int c = i * 16 + cg;
        int g = c >> 2;                   // granule (4 floats) index
        int cl = c & 3;
        float4 v = src4[(size_t)(b * 256 + c) * 1024 + (n0 >> 2) + n4l];
        // n = n4l*4 + r ; swizzled pos = ((g + (n>>2)) & 63)*4 + cl ; n>>2 = n4l
        int sw = ((g + n4l) & 63) * 4 + cl;
        tile[(n4l * 4 + 0) * 256 + sw] = v.x;
        tile[(n4l * 4 + 1) * 256 + sw] = v.y;
        tile[(n4l * 4 + 2) * 256 + sw] = v.z;
        tile[(n4l * 4 + 3) * 256 + sw] = v.w;
        ssv.x += v.x * v.x;  ssv.y += v.y * v.y;
        ssv.z += v.z * v.z;  ssv.w += v.w * v.w;
    }
    *reinterpret_cast<f32x4*>(&partial[cg * 64 + n4l * 4]) = ssv;
    __syncthreads();
    if (t < 64) {
        float s = 0.f;
#pragma unroll
        for (int g = 0; g < 16; ++g) s += partial[g * 64 + t];
        scale_s[t] = (which ? 1.0f : BETA_LOG2E) / fmaxf(sqrtf(s), EPSN);
    }
    __syncthreads();

    // phase 2: wave = one n-row per pass; lane g reads one swizzled float4,
    // emits 4 bf16 (8 B) -> 512 B contiguous store per wave.
    int wv = t >> 6;
    int g  = t & 63;
#pragma unroll
    for (int pass = 0; pass < 16; ++pass) {
        int n  = pass * 4 + wv;
        float sc = scale_s[n];
        int gp = (g + (n >> 2)) & 63;
        f32x4 u = *reinterpret_cast<const f32x4*>(&tile[n * 256 + gp * 4]);
        uint2 o;
        o.x = pack2bf(u.x * sc, u.y * sc);
        o.y = pack2bf(u.z * sc, u.w * sc);
        *reinterpret_cast<uint2*>(&dst[(size_t)(b * 4096 + n0 + n) * 256 + g * 4]) = o;
    }
}

// ---------------------------------------------------------------------------
// Kernel 2: flash cosine-sim + online softmax stats (no max shift needed:
// |logit*log2e| <= 14.43). grid = 128*nks: 4 batch x 32 qtile(128q) x nks.
// stats[q][ks] = {Z, Sx, Sy, Pmax}; aT pre-scaled so p = exp2(acc).
// NOTE: plain __launch_bounds__(256) — (256,4) forced VGPR=64 and spilled
// (R2: WRITE_SIZE 2->89 MB, FETCH 12->254 MB). Natural VGPR ~92 is correct.
// ---------------------------------------------------------------------------
__global__ __launch_bounds__(256) void k_flash(
    const unsigned short* __restrict__ aT, const unsigned short* __restrict__ bT,
    float* __restrict__ stats, int nks, int lg)
{
    __shared__ unsigned short kbuf[64 * 272];  // 64 keys x 272 hw (544 B rows)

    int idx   = blockIdx.x;
    int xcd   = idx & 7;                 // XCD swizzle: batch -> 2 XCDs
    int batch = xcd >> 1;
    int sub   = ((idx >> 3) << 1) | (xcd & 1);   // [0, 32*nks)
    int qt    = sub >> lg;               // [0,32)
    int ks    = sub & (nks - 1);         // [0,nks)
    int kps   = 4096 >> lg;              // keys per split
    int chunks = kps >> 6;

    int t    = threadIdx.x;
    int w    = t >> 6;
    int lane = t & 63;
    int quad = lane >> 4;
    int l15  = lane & 15;
    int q0w  = qt * 128 + w * 32;
    int k0   = ks * kps;

    // resident A fragments: 2 strips of 16 queries x 8 K-steps
    bf16x8 afrag[2][8];
#pragma unroll
    for (int s = 0; s < 2; ++s) {
        const unsigned short* ap =
            aT + ((size_t)(batch * 4096 + q0w + s * 16 + l15)) * 256 + quad * 8;
#pragma unroll
        for (int kk = 0; kk < 8; ++kk)
            afrag[s][kk] = *reinterpret_cast<const bf16x8*>(ap + kk * 32);
    }

    float Z[8], Sx[8], Sy[8], Pm[8], Zc[8];
#pragma unroll
    for (int i = 0; i < 8; ++i) { Z[i] = 0.f; Sx[i] = 0.f; Sy[i] = 0.f; Pm[i] = 0.f; Zc[i] = 0.f; }

    float kxl = (float)l15;

    for (int ch = 0; ch < chunks; ++ch) {
        int kbase = k0 + ch * 64;
        const unsigned short* gsrc = bT + ((size_t)(batch * 4096 + kbase)) * 256;
#pragma unroll
        for (int i = 0; i < 8; ++i) {
            int h = i * 2048 + t * 8;
            uint4 v = *reinterpret_cast<const uint4*>(gsrc + h);
            int key  = i * 8 + (t >> 5);
            int gran = t & 31;
            *reinterpret_cast<uint4*>(&kbuf[key * 272 + gran * 8]) = v;
        }
        __syncthreads();

#pragma unroll
        for (int nt = 0; nt < 4; ++nt) {
            f32x4 acc0 = {0.f, 0.f, 0.f, 0.f};
            f32x4 acc1 = {0.f, 0.f, 0.f, 0.f};
            const unsigned short* lp = &kbuf[(nt * 16 + l15) * 272 + quad * 8];
#pragma unroll
            for (int kk = 0; kk < 8; ++kk) {
                bf16x8 bfrag = *reinterpret_cast<const bf16x8*>(lp + kk * 32);
                acc0 = __builtin_amdgcn_mfma_f32_16x16x32_bf16(afrag[0][kk], bfrag, acc0, 0, 0, 0);
                acc1 = __builtin_amdgcn_mfma_f32_16x16x32_bf16(afrag[1][kk], bfrag, acc1, 0, 0, 0);
            }
            float kx = (float)(nt * 16) + kxl;   // key & 63 (kbase multiple of 64)
#pragma unroll
            for (int r = 0; r < 4; ++r) {
                float p0 = __builtin_amdgcn_exp2f(acc0[r]);
                Z[r] += p0;  Sx[r] += p0 * kx;  Pm[r] = fmaxf(Pm[r], p0);
                float p1 = __builtin_amdgcn_exp2f(acc1[r]);
                Z[4 + r] += p1;  Sx[4 + r] += p1 * kx;  Pm[4 + r] = fmaxf(Pm[4 + r], p1);
            }
        }
        __syncthreads();

        float ky = (float)(ks * chunks + ch);    // key >> 6, constant per chunk
#pragma unroll
        for (int i = 0; i < 8; ++i) {
            Sy[i] += ky * (Z[i] - Zc[i]);
            Zc[i] = Z[i];
        }
    }

    // reduce across the 16 col-lanes
#pragma unroll
    for (int i = 0; i < 8; ++i) {
#pragma unroll
        for (int m = 1; m <= 8; m <<= 1) {
            Z[i]  += __shfl_xor(Z[i], m);
            Sx[i] += __shfl_xor(Sx[i], m);
            Sy[i] += __shfl_xor(Sy[i], m);
            Pm[i]  = fmaxf(Pm[i], __shfl_xor(Pm[i], m));
        }
    }
    if (l15 == 0) {
#pragma unroll
        for (int s = 0; s < 2; ++s)
#pragma unroll
            for (int r = 0; r < 4; ++r) {
                int q = q0w + s * 16 + quad * 4 + r;
                f32x4 st = {Z[s * 4 + r], Sx[s * 4 + r], Sy[s * 4 + r], Pm[s * 4 + r]};
                *reinterpret_cast<f32x4*>(
                    &stats[((size_t)(batch * 4096 + q) * nks + ks) * 4]) = st;
            }
    }
}

// ---------------------------------------------------------------------------
// Kernel 3: merge key-splits, write warp (x,y interleaved) then cert.
// ---------------------------------------------------------------------------
__global__ __launch_bounds__(256) void k_finalize(
    const float* __restrict__ stats, float* __restrict__ out, int nks)
{
    int q = blockIdx.x * 256 + threadIdx.x;   // [0, 16384)
    const f32x4* s = reinterpret_cast<const f32x4*>(stats + (size_t)q * 4 * nks);
    float Z = 0.f, Sx = 0.f, Sy = 0.f, Pm = 0.f;
    for (int i = 0; i < nks; ++i) {
        f32x4 a = s[i];
        Z += a.x;  Sx += a.y;  Sy += a.z;  Pm = fmaxf(Pm, a.w);
    }
    float invZ = 1.0f / Z;
    out[q * 2 + 0]  = Sx * invZ;
    out[q * 2 + 1]  = Sy * invZ;
    out[32768 + q]  = Pm * invZ;
}

extern "C" void kernel_launch(void* const* d_in, const int* in_sizes, int n_in,
                              void* d_out, int out_size, void* d_ws, size_t ws_size,
                              hipStream_t stream)
{
    const float* f0 = (const float*)d_in[0];
    const float* f1 = (const float*)d_in[1];
    unsigned short* aT = (unsigned short*)d_ws;          // 8.39 MB
    unsigned short* bT = aT + (size_t)4 * 4096 * 256;    // 8.39 MB
    float* stats = (float*)(bT + (size_t)4 * 4096 * 256);
    float* out = (float*)d_out;

    size_t base = (size_t)2 * 4 * 4096 * 256 * 2;
    int nks = (ws_size >= base + (size_t)16384 * 8 * 16) ? 8 : 4;
    int lg  = (nks == 8) ? 3 : 2;

    hipLaunchKernelGGL(k_norm_transpose, dim3(512), dim3(256), 0, stream, f0, f1, aT, bT);
    hipLaunchKernelGGL(k_flash, dim3(128 * nks), dim3(256), 0, stream, aT, bT, stats, nks, lg);
    hipLaunchKernelGGL(k_finalize, dim3(64), dim3(256), 0, stream, stats, out, nks);
}